// Round 1
// 188.130 us; speedup vs baseline: 1.0132x; 1.0132x over previous
//
#include <hip/hip_runtime.h>
#include <hip/hip_bf16.h>
#include <cmath>

typedef float f32x16 __attribute__((ext_vector_type(16)));
typedef __bf16 bf16x8 __attribute__((ext_vector_type(8)));
typedef __bf16 bf16x4 __attribute__((ext_vector_type(4)));

#define NE 8
#define H 1024
#define DF 2048
#define WCOLS 16384
#define NTOK 4096
#define MROWS 8192
#define NBLK 64

// Wt layout: 2048 tiles of (256 cols x 1 kb-step). tile_id = (e*8+bxp)*32 + kb.
// Within a tile (8192 bf16 = 16KB): [group = col>>5][chunk = k>>3][row = col&31][8]
// This is EXACTLY the LDS image the GEMM wants, so staging is a linear copy and
// fragment reads are 1KB-contiguous per wave (zero bank conflicts).

typedef const __attribute__((address_space(1))) unsigned int glb_u32;
typedef __attribute__((address_space(3))) unsigned int lds_u32;

__device__ __forceinline__ void async_load16(const void* g, void* l) {
    __builtin_amdgcn_global_load_lds((glb_u32*)g, (lds_u32*)l, 16, 0, 0);
}

// ---- prep: blocks [0,1024) = router (+ x->bf16), [1024,5120) = w1 transpose -
__global__ __launch_bounds__(256) void prep_kernel(
    const float* __restrict__ x, const float* __restrict__ rw,
    const float* __restrict__ w1,
    float* __restrict__ logits, int* __restrict__ sel, float* __restrict__ rwn,
    __bf16* __restrict__ xb, __bf16* __restrict__ Wt)
{
    __shared__ float tile[32][132];
    int b = blockIdx.x;
    int tid = threadIdx.x;
    if (b < 1024) {
        // ---------------- router: 1 token per wave ----------------
        int tok  = b * 4 + (tid >> 6);
        int lane = tid & 63;
        const float* xr = x + (size_t)tok * H;
        __bf16* xbr = xb + (size_t)tok * H;
        float acc[NE];
#pragma unroll
        for (int e = 0; e < NE; ++e) acc[e] = 0.f;
#pragma unroll
        for (int it = 0; it < 4; ++it) {
            int k = (it * 64 + lane) * 4;
            float4 xv = *(const float4*)(xr + k);
            bf16x4 xc;
            xc[0] = (__bf16)xv.x; xc[1] = (__bf16)xv.y;
            xc[2] = (__bf16)xv.z; xc[3] = (__bf16)xv.w;
            *(bf16x4*)(xbr + k) = xc;
#pragma unroll
            for (int e = 0; e < NE; ++e) {
                float4 wv = *(const float4*)(rw + e * H + k);
                acc[e] += xv.x * wv.x + xv.y * wv.y + xv.z * wv.z + xv.w * wv.w;
            }
        }
#pragma unroll
        for (int e = 0; e < NE; ++e) {
            float v = acc[e];
#pragma unroll
            for (int off = 32; off > 0; off >>= 1) v += __shfl_xor(v, off, 64);
            acc[e] = v;
        }
        if (lane == 0) {
#pragma unroll
            for (int e = 0; e < NE; ++e) logits[tok * NE + e] = acc[e];
            int i1 = 0; float m1 = acc[0];
#pragma unroll
            for (int e = 1; e < NE; ++e) if (acc[e] > m1) { m1 = acc[e]; i1 = e; }
            int i2 = -1; float m2 = -INFINITY;
#pragma unroll
            for (int e = 0; e < NE; ++e) if (e != i1 && acc[e] > m2) { m2 = acc[e]; i2 = e; }
            float e2 = expf(m2 - m1);
            float inv = 1.f / (1.f + e2);
            sel[tok * 2]     = i1;  sel[tok * 2 + 1] = i2;
            rwn[tok * 2]     = inv; rwn[tok * 2 + 1] = e2 * inv;
        }
        return;
    }
    // -------- transpose into fragment-ordered Wt (see layout note above) ----
    int g  = b - 1024;                 // 0..4095
    int c  = g >> 5;                   // 128-col tile index, 0..127
    int kb = g & 31;
    int kk = tid >> 3;                 // 0..31
    int cc = (tid & 7) * 16;           // 0..112
    const float* src = w1 + (size_t)(kb * 32 + kk) * WCOLS + c * 128 + cc;
#pragma unroll
    for (int i = 0; i < 4; ++i) {
        float4 v = *(const float4*)(src + i * 4);
        *(float4*)&tile[kk][cc + i * 4] = v;
    }
    __syncthreads();
    int n = tid >> 1, kc0 = (tid & 1) * 16;
    bf16x8 o0, o1;
#pragma unroll
    for (int i = 0; i < 8; ++i) {
        o0[i] = (__bf16)tile[kc0 + i][n];       // k = kc0+i
        o1[i] = (__bf16)tile[kc0 + 8 + i][n];   // k = kc0+8+i
    }
    // global col = c*128 + n; tile pair = c>>1 (== (e*8+bxp)); half = c&1
    size_t tile_id = (size_t)(c >> 1) * 32 + kb;
    int group  = (c & 1) * 4 + (n >> 5);
    int chunk0 = kc0 >> 3;                       // 0 or 2
    __bf16* dst = Wt + tile_id * 8192 + group * 1024 + chunk0 * 256 + (n & 31) * 8;
    *(bf16x8*)dst         = o0;                  // chunk  chunk0
    *(bf16x8*)(dst + 256) = o1;                  // chunk  chunk0+1
}

// ------------- Stable counting sort by expert (1 block x 1024) --------------
__global__ __launch_bounds__(1024) void sort_kernel(
    const int* __restrict__ sel, const float* __restrict__ rwn,
    int* __restrict__ stok, float* __restrict__ srw, int* __restrict__ bexp)
{
    __shared__ int cnt[NE][1024];
    __shared__ int wtot[NE][2];
    __shared__ int ebase[NE + 1];
    int t = threadIdx.x;
    int selv[8];
    int lc[NE];
#pragma unroll
    for (int e = 0; e < NE; ++e) lc[e] = 0;
    int base = t * 8;
#pragma unroll
    for (int j = 0; j < 8; ++j) { selv[j] = sel[base + j]; lc[selv[j]]++; }
#pragma unroll
    for (int e = 0; e < NE; ++e) cnt[e][t] = lc[e];
    __syncthreads();
    // scan: expert g scanned by 128 threads (2 waves)
    int g = t >> 7, j = t & 127, jl = j & 63;
    int s = 0, pre[8];
#pragma unroll
    for (int i = 0; i < 8; ++i) { pre[i] = s; s += cnt[g][j * 8 + i]; }
    int inc = s;
#pragma unroll
    for (int d = 1; d < 64; d <<= 1) {
        int v = __shfl_up(inc, d, 64);
        if (jl >= d) inc += v;
    }
    if (jl == 63) wtot[g][j >> 6] = inc;
    __syncthreads();
    int add = (j >= 64) ? wtot[g][0] : 0;
    int excl = inc - s + add;
#pragma unroll
    for (int i = 0; i < 8; ++i) cnt[g][j * 8 + i] = excl + pre[i];
    __syncthreads();
    if (t == 0) {
        int acc = 0;
        for (int e = 0; e < NE; ++e) { ebase[e] = acc; acc += wtot[e][0] + wtot[e][1]; }
        ebase[NE] = acc;
    }
    __syncthreads();
    int off[NE];
#pragma unroll
    for (int e = 0; e < NE; ++e) off[e] = ebase[e] + cnt[e][t];
#pragma unroll
    for (int j2 = 0; j2 < 8; ++j2) {
        int i = base + j2;
        int e = selv[j2];
        int pos = off[e]++;
        stok[pos] = i >> 1;
        srw[pos]  = rwn[i];
    }
    __syncthreads();
    if (t < NBLK) {
        int r = t * 128;
        int e = 0;
        while (e < NE - 1 && r >= ebase[e + 1]) ++e;
        bexp[t] = e;
    }
}

// ---- Block GEMM: 128x256 tile, 4 waves x (64x128), conflict-free LDS -------
__global__ __launch_bounds__(256, 2) void moe_gemm(
    const __bf16* __restrict__ xb, const __bf16* __restrict__ Wt,
    const int* __restrict__ stok, const float* __restrict__ srw,
    const int* __restrict__ bexp, float* __restrict__ out)
{
    __shared__ __align__(16) __bf16 As[2][4096];   // [grp4][chunk4][row32][8]
    __shared__ __align__(16) __bf16 Bs[2][8192];   // [grp8][chunk4][row32][8]
    __shared__ int   tokS[128];
    __shared__ float rwS[128];

    int g = blockIdx.x;                        // 512 blocks
    // XCD swizzle: xcd = g&7 owns 8 consecutive by x all 8 bxp (B-tile reuse in L2)
    int by  = (g & 7) * 8 + ((g >> 3) & 7);    // 0..63
    int bxp = g >> 6;                          // 0..7  (256-col tiles)
    int tid = threadIdx.x;
    if (tid < 128) {
        tokS[tid] = stok[by * 128 + tid];
        rwS[tid]  = srw[by * 128 + tid];
    }
    int e = bexp[by];
    __syncthreads();

    int lane = tid & 63;
    int wv   = tid >> 6;
    int l32  = lane & 31;
    int hi   = lane >> 5;

    // A staging: wave wv owns rows [wv*32, wv*32+32); instr j covers chunks {2j,2j+1}
    const __bf16* aSrc = xb + (size_t)tokS[wv * 32 + l32] * H + hi * 8;
    __bf16* aDst0 = &As[0][wv * 1024 + lane * 8];
    __bf16* aDst1 = &As[1][wv * 1024 + lane * 8];

    // B staging: linear 16KB copy, wave wv copies bytes [wv*4KB, +4KB)
    const __bf16* bSrc = Wt + (size_t)(e * 8 + bxp) * 32 * 8192 + wv * 2048 + lane * 8;
    __bf16* bDst0 = &Bs[0][wv * 2048 + lane * 8];
    __bf16* bDst1 = &Bs[1][wv * 2048 + lane * 8];

    int wm = (wv & 1) * 64;                    // wave grid: 2(m) x 2(n)
    int wn = (wv >> 1) * 128;
    int ag = (wv & 1) * 2;                     // A group base
    int bg = (wv >> 1) * 4;                    // B group base

    f32x16 acc[2][4];
#pragma unroll
    for (int i = 0; i < 2; ++i)
#pragma unroll
        for (int j = 0; j < 4; ++j)
#pragma unroll
            for (int r = 0; r < 16; ++r) acc[i][j][r] = 0.f;

    // prologue: stage kb=0 into buffer 0
#pragma unroll
    for (int j = 0; j < 2; ++j) async_load16(aSrc + j * 16, aDst0 + j * 512);
#pragma unroll
    for (int j = 0; j < 4; ++j) async_load16(bSrc + j * 512, bDst0 + j * 512);

    for (int kb = 0; kb < 32; ++kb) {
        int cur = kb & 1;
        __syncthreads();               // drains vmcnt: buffer cur ready
        if (kb < 31) {
            const __bf16* aN = aSrc + (kb + 1) * 32;
            const __bf16* bN = bSrc + (size_t)(kb + 1) * 8192;
            __bf16* aD = cur ? aDst0 : aDst1;
            __bf16* bD = cur ? bDst0 : bDst1;
#pragma unroll
            for (int j = 0; j < 2; ++j) async_load16(aN + j * 16, aD + j * 512);
#pragma unroll
            for (int j = 0; j < 4; ++j) async_load16(bN + j * 512, bD + j * 512);
        }
        // fragment reads: each is 1KB contiguous per wave -> zero bank conflicts
        bf16x8 af[2][2], bfr[4][2];
#pragma unroll
        for (int h = 0; h < 2; ++h) {
#pragma unroll
            for (int ti = 0; ti < 2; ++ti)
                af[ti][h] = *(const bf16x8*)&As[cur][(ag + ti) * 1024 + (h * 2 + hi) * 256 + l32 * 8];
#pragma unroll
            for (int tj = 0; tj < 4; ++tj)
                bfr[tj][h] = *(const bf16x8*)&Bs[cur][(bg + tj) * 1024 + (h * 2 + hi) * 256 + l32 * 8];
        }
#pragma unroll
        for (int h = 0; h < 2; ++h)
#pragma unroll
            for (int ti = 0; ti < 2; ++ti)
#pragma unroll
                for (int tj = 0; tj < 4; ++tj)
                    acc[ti][tj] = __builtin_amdgcn_mfma_f32_32x32x16_bf16(
                        af[ti][h], bfr[tj][h], acc[ti][tj], 0, 0, 0);
    }

    // epilogue: gelu (tanh form) * rw; C/D: row=(reg&3)+8*(reg>>2)+4*(lane>>5)
    int rowh = hi * 4;
#pragma unroll
    for (int ti = 0; ti < 2; ++ti)
#pragma unroll
        for (int reg = 0; reg < 16; ++reg) {
            int row = (reg & 3) + 8 * (reg >> 2) + rowh;
            int m = wm + ti * 32 + row;
            float rw = rwS[m];
            size_t ob = (size_t)(by * 128 + m) * DF + bxp * 256 + wn + l32;
#pragma unroll
            for (int tj = 0; tj < 4; ++tj) {
                float val = acc[ti][tj][reg];
                float u = 0.7978845608028654f * val * (1.f + 0.044715f * val * val);
                float t = __expf(-2.f * fabsf(u));
                float th = (1.f - t) / (1.f + t);
                th = u < 0.f ? -th : th;
                out[ob + tj * 32] = 0.5f * val * (1.f + th) * rw;
            }
        }
}

extern "C" void kernel_launch(void* const* d_in, const int* in_sizes, int n_in,
                              void* d_out, int out_size, void* d_ws, size_t ws_size,
                              hipStream_t stream) {
    (void)in_sizes; (void)n_in; (void)out_size; (void)ws_size;
    const float* x        = (const float*)d_in[0];
    const float* router_w = (const float*)d_in[1];
    const float* w1       = (const float*)d_in[2];
    float* out    = (float*)d_out;
    float* logits = out + (size_t)MROWS * DF;

    char* ws    = (char*)d_ws;
    int*   sel  = (int*)(ws);
    float* rwn  = (float*)(ws + 0x8000);
    int*   stok = (int*)(ws + 0x10000);
    float* srw  = (float*)(ws + 0x18000);
    int*   bexp = (int*)(ws + 0x20000);
    __bf16* xb  = (__bf16*)(ws + (1 << 20));             // 8 MB
    __bf16* Wt  = (__bf16*)(ws + (1 << 20) + (8 << 20)); // 32 MB

    prep_kernel<<<5120, 256, 0, stream>>>(x, router_w, w1, logits, sel, rwn, xb, Wt);
    sort_kernel<<<1, 1024, 0, stream>>>(sel, rwn, stok, srw, bexp);
    moe_gemm<<<512, 256, 0, stream>>>(xb, Wt, stok, srw, bexp, out);
}